// Round 1
// baseline (190.953 us; speedup 1.0000x reference)
//
#include <hip/hip_runtime.h>

// Fused UpFIRDn2d: crop(1) -> +bias -> repeat-up x2 -> sep 12-tap FIR ->
// leaky_relu(0.2)*sqrt(2) -> sep 12-tap FIR -> downsample x2.
// Input x: (8,64,130,130) f32; out: (8,64,128,128) f32.
//
// Per-block: one 32x32 output tile of one (b,c) plane. All intermediates in LDS.
// Up-conv on the repeat-upsampled grid collapses to 6/7 combined taps per
// output phase: up-grid index m maps to base sample m>>1 (arithmetic shift
// = floor, so negative padding indices fall into the zero-padded region).

#define TH 32
#define TW 32
#define SLOPE_C 0.2f
#define GAIN_C 1.4142135623730951f

#define XP 44   // X LDS pitch (43 cols used)
#define AP 44   // A LDS pitch (43 cols used)
#define UPP 75  // U LDS pitch (74 cols used)
#define TP 75   // T LDS pitch (74 cols used)

__global__ __launch_bounds__(256) void upfirdn2d_fused(
    const float* __restrict__ xin_all,
    const float* __restrict__ bias,
    const float* __restrict__ fu_g,
    const float* __restrict__ fd_g,
    float* __restrict__ out)
{
    // XT: stages 0-1 holds X (43x44 = 1892 floats); stages 3-4 holds T (32x75 = 2400)
    __shared__ float XT[2400];
    __shared__ float A[74 * AP];   // 3256 floats
    __shared__ float U[74 * UPP];  // 5550 floats
    // total ~44.8 KB -> 3 blocks/CU

    const int tid = threadIdx.x;
    const int bc = blockIdx.z;
    const int i0 = blockIdx.y * TH;
    const int j0 = blockIdx.x * TW;

    // ---- filters into registers (uniform loads, L1/scalar-cached) ----
    float fdr[12];
#pragma unroll
    for (int k = 0; k < 12; ++k) fdr[k] = fd_g[k];

    float fu0 = fu_g[0], fu1 = fu_g[1], fu2 = fu_g[2], fu3 = fu_g[3];
    float fu4 = fu_g[4], fu5 = fu_g[5], fu6 = fu_g[6], fu7 = fu_g[7];
    float fu8 = fu_g[8], fu9 = fu_g[9], fu10 = fu_g[10], fu11 = fu_g[11];
    // combined up taps: odd local phase -> 7 taps ge[], even local phase -> 6 taps go[]
    const float ge0 = fu0,        ge1 = fu1 + fu2, ge2 = fu3 + fu4, ge3 = fu5 + fu6;
    const float ge4 = fu7 + fu8,  ge5 = fu9 + fu10, ge6 = fu11;
    const float go0 = fu0 + fu1,  go1 = fu2 + fu3, go2 = fu4 + fu5;
    const float go3 = fu6 + fu7,  go4 = fu8 + fu9, go5 = fu10 + fu11;

    const float bv = bias[bc & 63];
    const float* xin = xin_all + (size_t)bc * (130 * 130);

    // ---- Stage 0: load X tile (rows i0-5..i0+37, cols j0-5..j0+37), crop offset +1, +bias,
    //      zero outside [0,128)^2 ----
    for (int idx = tid; idx < 43 * 43; idx += 256) {
        int r = idx / 43, c = idx - r * 43;
        int gr = i0 - 5 + r, gc = j0 - 5 + c;
        float v = 0.f;
        if ((unsigned)gr < 128u && (unsigned)gc < 128u)
            v = xin[(gr + 1) * 130 + (gc + 1)] + bv;
        XT[r * XP + c] = v;
    }
    __syncthreads();

    // ---- Stage 1: H up-conv. A[pp][c] = up-grid row (2*i0-5+pp) conv over X rows ----
    for (int idx = tid; idx < 74 * 43; idx += 256) {
        int pp = idx / 43, c = idx - pp * 43;
        int odd = pp & 1;
        int rb = (pp - odd) >> 1;                 // base X row (local)
        float g0 = odd ? ge0 : go0;
        float g1 = odd ? ge1 : go1;
        float g2 = odd ? ge2 : go2;
        float g3 = odd ? ge3 : go3;
        float g4 = odd ? ge4 : go4;
        float g5 = odd ? ge5 : go5;
        float g6 = odd ? ge6 : 0.f;
        const float* Xc = &XT[rb * XP + c];
        float acc = Xc[0] * g0 + Xc[XP] * g1 + Xc[2 * XP] * g2 + Xc[3 * XP] * g3
                  + Xc[4 * XP] * g4 + Xc[5 * XP] * g5 + Xc[6 * XP] * g6;
        A[pp * AP + c] = acc;
    }
    __syncthreads();

    // ---- Stage 2: W up-conv + leaky-relu*gain. U[pp][qq] for up-grid
    //      (2*i0-5+pp, 2*j0-5+qq); zero outside the 256x256 up grid (this is the
    //      zero padding the down-conv expects) ----
    const int pbase = 2 * i0 - 5;
    const int qbase = 2 * j0 - 5;
    for (int idx = tid; idx < 74 * 74; idx += 256) {
        int pp = idx / 74, qq = idx - pp * 74;
        int pg = pbase + pp, qg = qbase + qq;
        float v = 0.f;
        if ((unsigned)pg < 256u && (unsigned)qg < 256u) {
            int odd = qq & 1;
            int cb = (qq - odd) >> 1;             // base A col (local)
            float g0 = odd ? ge0 : go0;
            float g1 = odd ? ge1 : go1;
            float g2 = odd ? ge2 : go2;
            float g3 = odd ? ge3 : go3;
            float g4 = odd ? ge4 : go4;
            float g5 = odd ? ge5 : go5;
            float g6 = odd ? ge6 : 0.f;
            const float* Ar = &A[pp * AP + cb];
            float acc = Ar[0] * g0 + Ar[1] * g1 + Ar[2] * g2 + Ar[3] * g3
                      + Ar[4] * g4 + Ar[5] * g5 + Ar[6] * g6;
            v = (acc >= 0.f ? acc : SLOPE_C * acc) * GAIN_C;
        }
        U[pp * UPP + qq] = v;
    }
    __syncthreads();

    // ---- Stage 3: H down-conv. T[ii][qq] = sum_k U[2*ii+k][qq] * fd[k] ----
    for (int idx = tid; idx < TH * 74; idx += 256) {
        int ii = idx / 74, qq = idx - ii * 74;
        const float* Uc = &U[(2 * ii) * UPP + qq];
        float acc = 0.f;
#pragma unroll
        for (int k = 0; k < 12; ++k) acc += Uc[k * UPP] * fdr[k];
        XT[ii * TP + qq] = acc;
    }
    __syncthreads();

    // ---- Stage 4: W down-conv + store ----
    float* outp = out + (size_t)bc * (128 * 128) + (size_t)i0 * 128 + j0;
    for (int idx = tid; idx < TH * TW; idx += 256) {
        int ii = idx >> 5, jj = idx & 31;
        const float* Tc = &XT[ii * TP + 2 * jj];
        float acc = 0.f;
#pragma unroll
        for (int k = 0; k < 12; ++k) acc += Tc[k] * fdr[k];
        outp[ii * 128 + jj] = acc;
    }
}

extern "C" void kernel_launch(void* const* d_in, const int* in_sizes, int n_in,
                              void* d_out, int out_size, void* d_ws, size_t ws_size,
                              hipStream_t stream) {
    const float* x  = (const float*)d_in[0];
    const float* bs = (const float*)d_in[1];
    const float* fu = (const float*)d_in[2];
    const float* fd = (const float*)d_in[3];
    float* out = (float*)d_out;

    dim3 grid(128 / TW, 128 / TH, 8 * 64);
    upfirdn2d_fused<<<grid, dim3(256), 0, stream>>>(x, bs, fu, fd, out);
}

// Round 2
// 159.148 us; speedup vs baseline: 1.1998x; 1.1998x over previous
//
#include <hip/hip_runtime.h>

// Fused UpFIRDn2d: crop(1) -> +bias -> repeat-up x2 -> sep 12-tap FIR ->
// leaky_relu(0.2)*sqrt(2) -> sep 12-tap FIR -> downsample x2.
// Input x: (8,64,130,130) f32; out: (8,64,128,128) f32.
//
// Round 2: phase-pair processing. Up-conv on the repeat-upsampled grid
// collapses to 6 combined taps (even phase, go[]) / 7 taps (odd phase, ge[]);
// both phases of a pair share one 7-wide base window -> compute pairs per
// thread: no per-point odd/even selects, half the iterations, float2 writes.
// Down-conv stages pair adjacent outputs (share 10 of 12 taps: 14 loads for
// 24 FMAs). Edge clipping hoisted to a block-uniform branch (interior tiles
// check-free).

#define SLOPE_C 0.2f
#define GAIN_C 1.4142135623730951f

#define XP 44   // X pitch (43x43 used)
#define AP 44   // A pitch (74x43 used)
#define UPP 76  // U pitch (74x74 used), even so float2 pair-writes are 8B aligned
#define TP 77   // T pitch (32x74 used), odd to cut stage-4 read conflicts to 4-way

__global__ __launch_bounds__(256) void upfirdn2d_fused(
    const float* __restrict__ xin_all,
    const float* __restrict__ bias,
    const float* __restrict__ fu_g,
    const float* __restrict__ fd_g,
    float* __restrict__ out)
{
    // XT: stages 0-1 hold X (43x44 = 1892); stages 3-4 hold T (32x77 = 2464)
    __shared__ __align__(16) float XT[32 * TP];     // 2464
    __shared__ __align__(16) float A[74 * AP];      // 3256
    __shared__ __align__(16) float U[74 * UPP];     // 5624
    // total 11344 floats = 44.3 KB -> 3 blocks/CU

    const int tid = threadIdx.x;
    const int bc = blockIdx.z;
    const int i0 = blockIdx.y * 32;
    const int j0 = blockIdx.x * 32;
    const bool edge = (blockIdx.x == 0) | (blockIdx.x == 3) |
                      (blockIdx.y == 0) | (blockIdx.y == 3);

    // ---- filters into registers ----
    float fdr[12];
#pragma unroll
    for (int k = 0; k < 12; ++k) fdr[k] = fd_g[k];
    float fu[12];
#pragma unroll
    for (int k = 0; k < 12; ++k) fu[k] = fu_g[k];
    // combined up-conv taps: even output phase -> go[0..5], odd -> ge[0..6]
    const float ge0 = fu[0],        ge1 = fu[1] + fu[2], ge2 = fu[3] + fu[4];
    const float ge3 = fu[5] + fu[6], ge4 = fu[7] + fu[8], ge5 = fu[9] + fu[10];
    const float ge6 = fu[11];
    const float go0 = fu[0] + fu[1], go1 = fu[2] + fu[3], go2 = fu[4] + fu[5];
    const float go3 = fu[6] + fu[7], go4 = fu[8] + fu[9], go5 = fu[10] + fu[11];

    const float bv = bias[bc & 63];
    const float* xin = xin_all + (size_t)bc * (130 * 130);

    // ---- Stage 0: X tile rows i0-5..i0+37, cols j0-5..j0+37 (crop +1, +bias) ----
    if (!edge) {
        const float* src = xin + (i0 - 4) * 130 + (j0 - 4);
        for (int idx = tid; idx < 43 * 43; idx += 256) {
            int r = idx / 43, c = idx - r * 43;
            XT[r * XP + c] = src[r * 130 + c] + bv;
        }
    } else {
        for (int idx = tid; idx < 43 * 43; idx += 256) {
            int r = idx / 43, c = idx - r * 43;
            int gr = i0 - 5 + r, gc = j0 - 5 + c;
            float v = 0.f;
            if ((unsigned)gr < 128u && (unsigned)gc < 128u)
                v = xin[(gr + 1) * 130 + (gc + 1)] + bv;
            XT[r * XP + c] = v;
        }
    }
    __syncthreads();

    // ---- Stage 1: H up-conv, row pairs. A[2m][c] (even, 6 taps), A[2m+1][c]
    //      (odd, 7 taps) share X rows m..m+6. 37 pairs x 43 cols. ----
    for (int idx = tid; idx < 37 * 43; idx += 256) {
        int m = idx / 43, c = idx - m * 43;
        const float* Xc = &XT[m * XP + c];
        float x0 = Xc[0], x1 = Xc[XP], x2 = Xc[2 * XP], x3 = Xc[3 * XP];
        float x4 = Xc[4 * XP], x5 = Xc[5 * XP], x6 = Xc[6 * XP];
        float ae = go0 * x0 + go1 * x1 + go2 * x2 + go3 * x3 + go4 * x4 + go5 * x5;
        float ao = ge0 * x0 + ge1 * x1 + ge2 * x2 + ge3 * x3 + ge4 * x4 + ge5 * x5
                 + ge6 * x6;
        A[(2 * m) * AP + c] = ae;
        A[(2 * m + 1) * AP + c] = ao;
    }
    __syncthreads();

    // ---- Stage 2: W up-conv + leaky*gain, col pairs. U[pp][2c], U[pp][2c+1]
    //      share A[pp][c..c+6]. 74 rows x 37 pairs. ----
    const int pbase = 2 * i0 - 5;
    const int qbase = 2 * j0 - 5;
    if (!edge) {
        for (int idx = tid; idx < 74 * 37; idx += 256) {
            int pp = idx / 37, c = idx - pp * 37;
            const float* Ar = &A[pp * AP + c];
            float a0 = Ar[0], a1 = Ar[1], a2 = Ar[2], a3 = Ar[3];
            float a4 = Ar[4], a5 = Ar[5], a6 = Ar[6];
            float ue = go0 * a0 + go1 * a1 + go2 * a2 + go3 * a3 + go4 * a4 + go5 * a5;
            float uo = ge0 * a0 + ge1 * a1 + ge2 * a2 + ge3 * a3 + ge4 * a4 + ge5 * a5
                     + ge6 * a6;
            ue = (ue >= 0.f) ? ue * GAIN_C : ue * (SLOPE_C * GAIN_C);
            uo = (uo >= 0.f) ? uo * GAIN_C : uo * (SLOPE_C * GAIN_C);
            *(float2*)&U[pp * UPP + 2 * c] = make_float2(ue, uo);
        }
    } else {
        for (int idx = tid; idx < 74 * 37; idx += 256) {
            int pp = idx / 37, c = idx - pp * 37;
            const float* Ar = &A[pp * AP + c];
            float a0 = Ar[0], a1 = Ar[1], a2 = Ar[2], a3 = Ar[3];
            float a4 = Ar[4], a5 = Ar[5], a6 = Ar[6];
            float ue = go0 * a0 + go1 * a1 + go2 * a2 + go3 * a3 + go4 * a4 + go5 * a5;
            float uo = ge0 * a0 + ge1 * a1 + ge2 * a2 + ge3 * a3 + ge4 * a4 + ge5 * a5
                     + ge6 * a6;
            ue = (ue >= 0.f) ? ue * GAIN_C : ue * (SLOPE_C * GAIN_C);
            uo = (uo >= 0.f) ? uo * GAIN_C : uo * (SLOPE_C * GAIN_C);
            unsigned pg = (unsigned)(pbase + pp);
            unsigned qe = (unsigned)(qbase + 2 * c);
            unsigned qo = qe + 1u;   // wraps correctly for qe == -1
            if (!(pg < 256u && qe < 256u)) ue = 0.f;
            if (!(pg < 256u && qo < 256u)) uo = 0.f;
            *(float2*)&U[pp * UPP + 2 * c] = make_float2(ue, uo);
        }
    }
    __syncthreads();

    // ---- Stage 3: H down-conv, output-row pairs. T[2a][qq], T[2a+1][qq]
    //      share U rows 4a+2..4a+11 (14 loads, 24 FMAs). 16 pairs x 74 cols. ----
    for (int idx = tid; idx < 16 * 74; idx += 256) {
        int a = idx / 74, qq = idx - a * 74;
        const float* Uc = &U[(4 * a) * UPP + qq];
        float u[14];
#pragma unroll
        for (int k = 0; k < 14; ++k) u[k] = Uc[k * UPP];
        float t0 = 0.f, t1 = 0.f;
#pragma unroll
        for (int k = 0; k < 12; ++k) { t0 += fdr[k] * u[k]; t1 += fdr[k] * u[k + 2]; }
        XT[(2 * a) * TP + qq] = t0;
        XT[(2 * a + 1) * TP + qq] = t1;
    }
    __syncthreads();

    // ---- Stage 4: W down-conv, output-col pairs + float2 store.
    //      32 rows x 16 pairs = 512 iters (exactly 2 per thread). ----
    float* outp = out + (size_t)bc * (128 * 128) + (size_t)i0 * 128 + j0;
    {
        int idx = tid;
#pragma unroll
        for (int it = 0; it < 2; ++it, idx += 256) {
            int ii = idx >> 4, a = idx & 15;
            const float* Tc = &XT[ii * TP + 4 * a];
            float t[14];
#pragma unroll
            for (int k = 0; k < 14; ++k) t[k] = Tc[k];
            float o0 = 0.f, o1 = 0.f;
#pragma unroll
            for (int k = 0; k < 12; ++k) { o0 += fdr[k] * t[k]; o1 += fdr[k] * t[k + 2]; }
            *(float2*)&outp[ii * 128 + 2 * a] = make_float2(o0, o1);
        }
    }
}

extern "C" void kernel_launch(void* const* d_in, const int* in_sizes, int n_in,
                              void* d_out, int out_size, void* d_ws, size_t ws_size,
                              hipStream_t stream) {
    const float* x  = (const float*)d_in[0];
    const float* bs = (const float*)d_in[1];
    const float* fu = (const float*)d_in[2];
    const float* fd = (const float*)d_in[3];
    float* out = (float*)d_out;

    dim3 grid(4, 4, 8 * 64);
    upfirdn2d_fused<<<grid, dim3(256), 0, stream>>>(x, bs, fu, fd, out);
}

// Round 3
// 152.341 us; speedup vs baseline: 1.2535x; 1.0447x over previous
//
#include <hip/hip_runtime.h>

// Fused UpFIRDn2d: crop(1) -> +bias -> repeat-up x2 -> sep 12-tap FIR ->
// leaky_relu(0.2)*sqrt(2) -> sep 12-tap FIR -> downsample x2.
// Input x: (8,64,130,130) f32; out: (8,64,128,128) f32.
//
// Round 3: LDS-traffic restructure (round 2 was LDS-issue-bound).
//  - Conv order swapped to W-up, H-up, H-down, W-down (separable convs commute).
//  - S1 (W-up) reads its sliding windows straight from GLOBAL (L1/L2-served,
//    plane = 67 KB); bias folded in; X LDS buffer + a barrier deleted.
//  - S23: H-up + leaky*gain + H-down FUSED in registers: thread owns column qq,
//    slides a 7-tap window down B (1 LDS read/step) and retires u-values into
//    8 ring accumulators; U buffer (biggest LDS array + traffic) deleted.
//  - S4 (W-down): b128 LDS reads + float4 global stores.
// LDS: B 43x76 + T 32x76 = 22.8 KB (was 45 KB).

#define SLOPE_C 0.2f
#define GAIN_C 1.4142135623730951f
#define SG_C (SLOPE_C * GAIN_C)

#define BP 76   // B pitch (43 rows x 74 cols used); even -> aligned float2 pair writes
#define TP 76   // T pitch (32 rows x 74 cols used); mult of 4 -> aligned float4 reads

__global__ __launch_bounds__(256) void upfirdn2d_fused(
    const float* __restrict__ xin_all,
    const float* __restrict__ bias,
    const float* __restrict__ fu_g,
    const float* __restrict__ fd_g,
    float* __restrict__ out)
{
    __shared__ __align__(16) float Bsh[43 * BP];   // W-up-conv result
    __shared__ __align__(16) float Tsh[32 * TP];   // after fused H-up/leaky/H-down

    const int tid = threadIdx.x;
    const int bc  = blockIdx.z;
    const int i0  = blockIdx.y * 32;
    const int j0  = blockIdx.x * 32;
    const bool edge = (blockIdx.x == 0) | (blockIdx.x == 3) |
                      (blockIdx.y == 0) | (blockIdx.y == 3);

    float fdr[12];
#pragma unroll
    for (int k = 0; k < 12; ++k) fdr[k] = fd_g[k];
    float fuv[12];
#pragma unroll
    for (int k = 0; k < 12; ++k) fuv[k] = fu_g[k];
    // combined up-conv taps: even output phase -> go[0..5], odd -> ge[0..6]
    const float ge0 = fuv[0],          ge1 = fuv[1] + fuv[2], ge2 = fuv[3] + fuv[4];
    const float ge3 = fuv[5] + fuv[6], ge4 = fuv[7] + fuv[8], ge5 = fuv[9] + fuv[10];
    const float ge6 = fuv[11];
    const float go0 = fuv[0] + fuv[1], go1 = fuv[2] + fuv[3], go2 = fuv[4] + fuv[5];
    const float go3 = fuv[6] + fuv[7], go4 = fuv[8] + fuv[9], go5 = fuv[10] + fuv[11];

    const float bv = bias[bc & 63];
    const float* __restrict__ xin = xin_all + (size_t)bc * (130 * 130);

    // ---- S1: W up-conv, global -> Bsh. Item (r, s): B row r (0..42),
    //      pair-segment s (0..5) of up to 7 col-pairs. 43*6 = 258 items. ----
    for (int idx = tid; idx < 258; idx += 256) {
        const int r = idx / 6;
        const int s = idx - r * 6;
        const int grow = i0 - 5 + r;          // x-grid row of this B row
        const int gc0  = j0 - 5 + 7 * s;      // x-grid col of window element 0
        float w[13];
        if (!edge) {
            const float* src = xin + (grow + 1) * 130 + (gc0 + 1);
#pragma unroll
            for (int i = 0; i < 13; ++i) w[i] = src[i] + bv;
        } else if ((unsigned)grow < 128u) {
            const float* src = xin + (grow + 1) * 130 + 1;
#pragma unroll
            for (int i = 0; i < 13; ++i) {
                int gc = gc0 + i;
                int gcc = gc < 0 ? 0 : (gc > 127 ? 127 : gc);
                w[i] = ((unsigned)gc < 128u) ? src[gcc] + bv : 0.f;
            }
        } else {
#pragma unroll
            for (int i = 0; i < 13; ++i) w[i] = 0.f;
        }
        float* brow = &Bsh[r * BP + 14 * s];
#pragma unroll
        for (int p = 0; p < 7; ++p) {
            if (7 * s + p < 37) {
                float be = go0 * w[p] + go1 * w[p+1] + go2 * w[p+2] + go3 * w[p+3]
                         + go4 * w[p+4] + go5 * w[p+5];
                float bo = ge0 * w[p] + ge1 * w[p+1] + ge2 * w[p+2] + ge3 * w[p+3]
                         + ge4 * w[p+4] + ge5 * w[p+5] + ge6 * w[p+6];
                *(float2*)&brow[2 * p] = make_float2(be, bo);
            }
        }
    }
    __syncthreads();

    // ---- S23: fused H-up-conv + leaky*gain + H-down-conv, in registers.
    //      Item (s, qq): T rows 8s..8s+7, column qq. 4*74 = 296 items.
    //      Slide B rows 8s..8s+18; step t handles up-rows pair (16s+2t, +1);
    //      u feeds T rows a with tap k = (pp - 2*(8s+a)). ----
    const int pb = 2 * i0 - 5;
    const int qb = 2 * j0 - 5;
    for (int idx = tid; idx < 296; idx += 256) {
        const int s  = idx / 74;
        const int qq = idx - s * 74;
        const float* bcol = &Bsh[(8 * s) * BP + qq];
        const bool colok = ((unsigned)(qb + qq) < 256u);
        const int pe0 = pb + 16 * s;
        float acc[8];
#pragma unroll
        for (int a = 0; a < 8; ++a) acc[a] = 0.f;
        float w[7];
#pragma unroll
        for (int j = 0; j < 6; ++j) w[j] = bcol[j * BP];
#pragma unroll
        for (int t = 0; t < 13; ++t) {
            w[6] = bcol[(t + 6) * BP];
            float ue = go0 * w[0] + go1 * w[1] + go2 * w[2] + go3 * w[3]
                     + go4 * w[4] + go5 * w[5];
            float uo = ge0 * w[0] + ge1 * w[1] + ge2 * w[2] + ge3 * w[3]
                     + ge4 * w[4] + ge5 * w[5] + ge6 * w[6];
            if (edge) {
                int pe = pe0 + 2 * t;
                if (!colok || (unsigned)pe >= 256u)       ue = 0.f;
                if (!colok || (unsigned)(pe + 1) >= 256u) uo = 0.f;
            }
            // leaky_relu * gain without compare: G*max(x,0) + S*G*min(x,0)
            ue = fmaxf(ue, 0.f) * GAIN_C + fminf(ue, 0.f) * SG_C;
            uo = fmaxf(uo, 0.f) * GAIN_C + fminf(uo, 0.f) * SG_C;
#pragma unroll
            for (int a = 0; a < 8; ++a) {
                if (a <= t && a >= t - 5) {
                    acc[a] += ue * fdr[2 * (t - a)] + uo * fdr[2 * (t - a) + 1];
                }
            }
            if (t >= 5) Tsh[(8 * s + (t - 5)) * TP + qq] = acc[t - 5];
#pragma unroll
            for (int j = 0; j < 6; ++j) w[j] = w[j + 1];
        }
    }
    __syncthreads();

    // ---- S4: W down-conv + float4 store. Thread = (row ii, 4-col group g). ----
    {
        const int ii = tid >> 3;
        const int g  = tid & 7;
        const float* trow = &Tsh[ii * TP + 8 * g];   // (76*ii + 8g) % 4 == 0: 16B aligned
        float t0[18];
        *(float4*)&t0[0]  = *(const float4*)&trow[0];
        *(float4*)&t0[4]  = *(const float4*)&trow[4];
        *(float4*)&t0[8]  = *(const float4*)&trow[8];
        *(float4*)&t0[12] = *(const float4*)&trow[12];
        *(float2*)&t0[16] = *(const float2*)&trow[16];
        float o0 = 0.f, o1 = 0.f, o2 = 0.f, o3 = 0.f;
#pragma unroll
        for (int k = 0; k < 12; ++k) {
            float f = fdr[k];
            o0 += f * t0[k];
            o1 += f * t0[k + 2];
            o2 += f * t0[k + 4];
            o3 += f * t0[k + 6];
        }
        float* op = out + (size_t)bc * (128 * 128) + (size_t)(i0 + ii) * 128
                  + (j0 + 4 * g);
        *(float4*)op = make_float4(o0, o1, o2, o3);
    }
}

extern "C" void kernel_launch(void* const* d_in, const int* in_sizes, int n_in,
                              void* d_out, int out_size, void* d_ws, size_t ws_size,
                              hipStream_t stream) {
    const float* x  = (const float*)d_in[0];
    const float* bs = (const float*)d_in[1];
    const float* fu = (const float*)d_in[2];
    const float* fd = (const float*)d_in[3];
    float* out = (float*)d_out;

    dim3 grid(4, 4, 8 * 64);
    upfirdn2d_fused<<<grid, dim3(256), 0, stream>>>(x, bs, fu, fd, out);
}

// Round 4
// 140.782 us; speedup vs baseline: 1.3564x; 1.0821x over previous
//
#include <hip/hip_runtime.h>

// Fused UpFIRDn2d: crop(1) -> +bias -> repeat-up x2 -> sep 12-tap FIR ->
// leaky_relu(0.2)*sqrt(2) -> sep 12-tap FIR -> downsample x2.
// Input x: (8,64,130,130) f32; out: (8,64,128,128) f32.
//
// Round 4: issue-balance fixes (round 3 had 41% no-issue cycles from work
// counts not dividing by 256 -> multi-pass wave tails at both barriers).
//  - 320-thread blocks: S1 (258 items), S23 (296), S4 (256) all single-pass.
//  - S1 last column-segment overlaps (identical values double-written) ->
//    straight-line 7-pair bodies, no per-pair bound checks.
//  - edge split into colEdge (bx 0,3: per-element clip) and rowEdge (by 0,3:
//    cheap uniform row check); 8/16 blocks now take the fast S1 path.
//  - leaky*gain as 3 ops: G*u + (SG-G)*min(u,0).
// LDS: B 43x76 + T 32x76 = 22.3 KB -> 6 blocks/CU (30 waves).

#define SLOPE_C 0.2f
#define GAIN_C 1.4142135623730951f
#define NEG_C ((SLOPE_C - 1.0f) * GAIN_C)   // SG - G

#define BP 76   // B pitch (43 rows x 74 cols used)
#define TP 76   // T pitch (32 rows x 74 cols used); mult of 4 -> aligned float4

__global__ __launch_bounds__(320) void upfirdn2d_fused(
    const float* __restrict__ xin_all,
    const float* __restrict__ bias,
    const float* __restrict__ fu_g,
    const float* __restrict__ fd_g,
    float* __restrict__ out)
{
    __shared__ __align__(16) float Bsh[43 * BP];   // W-up-conv result
    __shared__ __align__(16) float Tsh[32 * TP];   // after fused H-up/leaky/H-down

    const int tid = threadIdx.x;
    const int bc  = blockIdx.z;
    const int i0  = blockIdx.y * 32;
    const int j0  = blockIdx.x * 32;
    const bool colEdge = (blockIdx.x == 0) | (blockIdx.x == 3);
    const bool rowEdge = (blockIdx.y == 0) | (blockIdx.y == 3);

    float fdr[12];
#pragma unroll
    for (int k = 0; k < 12; ++k) fdr[k] = fd_g[k];
    float fuv[12];
#pragma unroll
    for (int k = 0; k < 12; ++k) fuv[k] = fu_g[k];
    // combined up-conv taps: one phase uses go[0..5], the other ge[0..6]
    const float ge0 = fuv[0],          ge1 = fuv[1] + fuv[2], ge2 = fuv[3] + fuv[4];
    const float ge3 = fuv[5] + fuv[6], ge4 = fuv[7] + fuv[8], ge5 = fuv[9] + fuv[10];
    const float ge6 = fuv[11];
    const float go0 = fuv[0] + fuv[1], go1 = fuv[2] + fuv[3], go2 = fuv[4] + fuv[5];
    const float go3 = fuv[6] + fuv[7], go4 = fuv[8] + fuv[9], go5 = fuv[10] + fuv[11];

    const float bv = bias[bc & 63];
    const float* __restrict__ xin = xin_all + (size_t)bc * (130 * 130);

    // ---- S1: W up-conv, global -> Bsh. Item (r, s): B row r (0..42), segment s
    //      (0..5) of 7 col-pairs. Segment 5 starts at pair 30 (overlaps seg 4;
    //      identical values double-written -> benign). 258 items, one pass. ----
    if (tid < 258) {
        const int r = tid / 6;
        const int s = tid - r * 6;
        const int startP = (s == 5) ? 30 : 7 * s;
        const int grow = i0 - 5 + r;          // x-grid row of this B row
        const int gc0  = j0 - 5 + startP;     // x-grid col of window element 0
        float* brow = &Bsh[r * BP + 2 * startP];
        if ((unsigned)grow < 128u) {
            float w[13];
            if (!colEdge) {
                const float* src = xin + (grow + 1) * 130 + (gc0 + 1);
#pragma unroll
                for (int i = 0; i < 13; ++i) w[i] = src[i] + bv;
            } else {
                const float* src = xin + (grow + 1) * 130 + 1;
#pragma unroll
                for (int i = 0; i < 13; ++i) {
                    int gc = gc0 + i;
                    int gcc = gc < 0 ? 0 : (gc > 127 ? 127 : gc);
                    w[i] = ((unsigned)gc < 128u) ? src[gcc] + bv : 0.f;
                }
            }
#pragma unroll
            for (int p = 0; p < 7; ++p) {
                float be = go0 * w[p] + go1 * w[p+1] + go2 * w[p+2] + go3 * w[p+3]
                         + go4 * w[p+4] + go5 * w[p+5];
                float bo = ge0 * w[p] + ge1 * w[p+1] + ge2 * w[p+2] + ge3 * w[p+3]
                         + ge4 * w[p+4] + ge5 * w[p+5] + ge6 * w[p+6];
                *(float2*)&brow[2 * p] = make_float2(be, bo);
            }
        } else {
#pragma unroll
            for (int p = 0; p < 7; ++p)
                *(float2*)&brow[2 * p] = make_float2(0.f, 0.f);
        }
    }
    __syncthreads();

    // ---- S23: fused H-up-conv + leaky*gain + H-down-conv, in registers.
    //      Item (s, qq): T rows 8s..8s+7, column qq. 296 items, one pass.
    //      Slide B rows 8s..8s+18; step t handles up-row pair; u feeds the
    //      8 ring accumulators with tap k = pp - 2*(8s+a). ----
    const int pb = 2 * i0 - 5;
    const int qb = 2 * j0 - 5;
    const bool edgeAny = colEdge | rowEdge;
    if (tid < 296) {
        const int s  = tid / 74;
        const int qq = tid - s * 74;
        const float* bcol = &Bsh[(8 * s) * BP + qq];
        const bool cok = !colEdge || ((unsigned)(qb + qq) < 256u);
        const int pe0 = pb + 16 * s;
        float acc[8];
#pragma unroll
        for (int a = 0; a < 8; ++a) acc[a] = 0.f;
        float w[7];
#pragma unroll
        for (int j = 0; j < 6; ++j) w[j] = bcol[j * BP];
#pragma unroll
        for (int t = 0; t < 13; ++t) {
            w[6] = bcol[(t + 6) * BP];
            float ue = go0 * w[0] + go1 * w[1] + go2 * w[2] + go3 * w[3]
                     + go4 * w[4] + go5 * w[5];
            float uo = ge0 * w[0] + ge1 * w[1] + ge2 * w[2] + ge3 * w[3]
                     + ge4 * w[4] + ge5 * w[5] + ge6 * w[6];
            if (edgeAny) {
                int pe = pe0 + 2 * t;
                if (!cok || (unsigned)pe >= 256u)       ue = 0.f;
                if (!cok || (unsigned)(pe + 1) >= 256u) uo = 0.f;
            }
            // leaky_relu * gain: G*u + (SG-G)*min(u,0)  (3 ops)
            ue = GAIN_C * ue + NEG_C * fminf(ue, 0.f);
            uo = GAIN_C * uo + NEG_C * fminf(uo, 0.f);
#pragma unroll
            for (int a = 0; a < 8; ++a) {
                if (a <= t && a >= t - 5) {
                    acc[a] += ue * fdr[2 * (t - a)] + uo * fdr[2 * (t - a) + 1];
                }
            }
            if (t >= 5) Tsh[(8 * s + (t - 5)) * TP + qq] = acc[t - 5];
#pragma unroll
            for (int j = 0; j < 6; ++j) w[j] = w[j + 1];
        }
    }
    __syncthreads();

    // ---- S4: W down-conv + float4 store. Thread = (row ii, 4-col group g).
    //      256 items, one pass. ----
    if (tid < 256) {
        const int ii = tid >> 3;
        const int g  = tid & 7;
        const float* trow = &Tsh[ii * TP + 8 * g];   // 16B aligned
        float t0[18];
        *(float4*)&t0[0]  = *(const float4*)&trow[0];
        *(float4*)&t0[4]  = *(const float4*)&trow[4];
        *(float4*)&t0[8]  = *(const float4*)&trow[8];
        *(float4*)&t0[12] = *(const float4*)&trow[12];
        *(float2*)&t0[16] = *(const float2*)&trow[16];
        float o0 = 0.f, o1 = 0.f, o2 = 0.f, o3 = 0.f;
#pragma unroll
        for (int k = 0; k < 12; ++k) {
            float f = fdr[k];
            o0 += f * t0[k];
            o1 += f * t0[k + 2];
            o2 += f * t0[k + 4];
            o3 += f * t0[k + 6];
        }
        float* op = out + (size_t)bc * (128 * 128) + (size_t)(i0 + ii) * 128
                  + (j0 + 4 * g);
        *(float4*)op = make_float4(o0, o1, o2, o3);
    }
}

extern "C" void kernel_launch(void* const* d_in, const int* in_sizes, int n_in,
                              void* d_out, int out_size, void* d_ws, size_t ws_size,
                              hipStream_t stream) {
    const float* x  = (const float*)d_in[0];
    const float* bs = (const float*)d_in[1];
    const float* fu = (const float*)d_in[2];
    const float* fd = (const float*)d_in[3];
    float* out = (float*)d_out;

    dim3 grid(4, 4, 8 * 64);
    upfirdn2d_fused<<<grid, dim3(320), 0, stream>>>(x, bs, fu, fd, out);
}